// Round 6
// baseline (48107.974 us; speedup 1.0000x reference)
//
#include <hip/hip_runtime.h>
#include <math.h>

static constexpr int Bz = 128;
static constexpr int Tt = 1024;
static constexpr int Hh = 512;
static constexpr int Cc = 10;

static constexpr int NXCD = 8;       // XCDs; each runs an independent group
static constexpr int BPX  = 32;      // blocks (CUs) per XCD
static constexpr int UPB  = 16;      // hidden units per block (64 gate rows)
static constexpr int NB   = 16;      // batch rows per XCD (8*16 = 128)
static constexpr int THREADS = 256;
static constexpr int GRID = 256;     // 1 block per CU (LDS-forced)

// ws bytes: [0,1024)   barrier cnt[8], stride 32 ints (one line per XCD)
//           [1024,2048) rank counters[8], stride 32 ints
//           [4096,...)  h[2][8][16][512] fp32
static constexpr size_t WS_H_F  = 1024;   // float offset of h
static constexpr size_t WS_H_F4 = 256;    // float4 offset of h

__device__ __forceinline__ float dot4(float4 a, float4 b) {
    return a.x * b.x + a.y * b.y + a.z * b.z + a.w * b.w;
}

__global__ __launch_bounds__(THREADS, 1)
void lstm_fused(const float* __restrict__ x,
                const float* __restrict__ w_ih,
                const float* __restrict__ w_hh,
                const float* __restrict__ b_ih,
                const float* __restrict__ b_hh,
                const float* __restrict__ w_t,
                const float* __restrict__ w_fc,
                const float* __restrict__ b_fc,
                float* __restrict__ out,
                float* __restrict__ ws)
{
    const int tid  = threadIdx.x;
    const int lane = tid & 63;
    const int wv   = tid >> 6;        // wave id = gate id in GEMM
    const int ks   = lane & 15;       // K-slice lane
    const int bg   = lane >> 4;       // batch group (4 rows each)

    int*    bar      = (int*)ws;            // [xcd*32]
    int*    counters = (int*)ws + 256;      // [xcd*32]
    float*  hglob    = ws + WS_H_F;
    float4* h4       = (float4*)ws + WS_H_F4;

    // LDS: w slice 128 KB + h tile 32 KB = exactly 160 KiB (gbuf aliases hls)
    __shared__ float4 wls[64 * 128];
    __shared__ float4 hls[16 * 128];
    float* gbuf = (float*)hls;        // 64 x 17 floats, used only post-GEMM

    // ---- discover physical XCD, claim a rank (exchange aliased into hls) ----
    int* xchg = (int*)hls;            // hls is dead until loop phase A
    if (tid == 0) {
        int xr;
        asm volatile("s_getreg_b32 %0, hwreg(20, 0, 32)" : "=s"(xr));
        const int xcd = xr & 7;
        xchg[0] = xcd;
        xchg[1] = atomicAdd(&counters[xcd * 32], 1) & 31;   // device-scope RMW
    }
    __syncthreads();
    const int xcd  = xchg[0];
    const int rank = xchg[1];
    __syncthreads();                  // everyone read before hls is reused
    int* mycnt = &bar[xcd * 32];

    // ---- preload w_hh slice: rows g*512 + rank*16 + j  ->  wls[g*16+j] ----
    {
        const float4* w4 = (const float4*)w_hh;
        #pragma unroll
        for (int g = 0; g < 4; ++g)
            #pragma unroll
            for (int n = 0; n < 8; ++n) {
                const int idx = n * 256 + tid;        // 0..2047
                const int j = idx >> 7, col = idx & 127;
                wls[(g * UPB + j) * 128 + col] =
                    w4[(size_t)(g * Hh + rank * UPB + j) * 128 + col];
            }
    }

    // ---- elementwise role: thread -> (u, b) ----
    const int u  = tid & 15;
    const int b_ = tid >> 4;                 // 0..15
    const int gj = rank * UPB + u;           // global hidden unit
    const int gb = xcd * NB + b_;            // global batch row
    float wih_r[4], bias_r[4];
    #pragma unroll
    for (int g = 0; g < 4; ++g) {
        wih_r[g]  = w_ih[g * Hh + gj];
        bias_r[g] = b_ih[g * Hh + gj] + b_hh[g * Hh + gj];
    }
    float creg = 0.0f;

    // ---- owner role: ranks 0..15 own batch row xcd*16+rank ----
    const bool owner = (rank < NB);
    const int  gb_own = xcd * NB + rank;
    float S1w[Cc], S2w[Cc], bfc_r[Cc];
    #pragma unroll
    for (int c = 0; c < Cc; ++c) { S1w[c] = 0.f; S2w[c] = 0.f; bfc_r[c] = b_fc[c]; }

    for (int t = 0; t < Tt; ++t) {
        const int rb = t & 1, wb = rb ^ 1;

        // ---- A: stage h_t (16 x 512) into LDS (XCD-L2-local, plain loads) ----
        if (t == 0) {
            const float4 z = make_float4(0.f, 0.f, 0.f, 0.f);
            #pragma unroll
            for (int n = 0; n < 8; ++n) hls[n * 256 + tid] = z;
        } else {
            const float4* src = h4 + (size_t)(rb * NXCD + xcd) * 2048;
            #pragma unroll
            for (int n = 0; n < 8; ++n) hls[n * 256 + tid] = src[n * 256 + tid];
        }
        __syncthreads();

        // ---- B: GEMM 64x16x512, wave = gate, 16x4 reg tile, K split 16 ----
        float acc[16][4];
        #pragma unroll
        for (int j = 0; j < 16; ++j)
            #pragma unroll
            for (int i = 0; i < 4; ++i) acc[j][i] = 0.f;

        #pragma unroll
        for (int q = 0; q < 8; ++q) {
            const int kq = ks + q * 16;
            float4 hv[4];
            #pragma unroll
            for (int i = 0; i < 4; ++i) hv[i] = hls[(bg * 4 + i) * 128 + kq];
            #pragma unroll
            for (int j2 = 0; j2 < 2; ++j2) {
                float4 wf[8];
                #pragma unroll
                for (int j = 0; j < 8; ++j)
                    wf[j] = wls[(wv * UPB + j2 * 8 + j) * 128 + kq];
                #pragma unroll
                for (int j = 0; j < 8; ++j)
                    #pragma unroll
                    for (int i = 0; i < 4; ++i)
                        acc[j2 * 8 + j][i] += wf[j].x * hv[i].x + wf[j].y * hv[i].y
                                            + wf[j].z * hv[i].z + wf[j].w * hv[i].w;
            }
        }
        #pragma unroll
        for (int m = 1; m <= 8; m <<= 1)
            #pragma unroll
            for (int j = 0; j < 16; ++j)
                #pragma unroll
                for (int i = 0; i < 4; ++i)
                    acc[j][i] += __shfl_xor(acc[j][i], m, 64);

        __syncthreads();          // all hls reads done before gbuf clobbers it
        if (ks == 0) {
            #pragma unroll
            for (int j = 0; j < 16; ++j)
                #pragma unroll
                for (int i = 0; i < 4; ++i)
                    gbuf[(wv * UPB + j) * 17 + (bg * 4 + i)] = acc[j][i];
        }
        __syncthreads();

        // ---- C: LSTM elementwise, write h_t+1 (plain store -> XCD L2) ----
        {
            const float xv = x[(size_t)gb * Tt + t];
            const float gi = gbuf[(0 * UPB + u) * 17 + b_] + xv * wih_r[0] + bias_r[0];
            const float gf = gbuf[(1 * UPB + u) * 17 + b_] + xv * wih_r[1] + bias_r[1];
            const float gg = gbuf[(2 * UPB + u) * 17 + b_] + xv * wih_r[2] + bias_r[2];
            const float go = gbuf[(3 * UPB + u) * 17 + b_] + xv * wih_r[3] + bias_r[3];
            const float si = 1.f / (1.f + expf(-gi));
            const float sf = 1.f / (1.f + expf(-gf));
            const float so = 1.f / (1.f + expf(-go));
            creg = sf * creg + si * tanhf(gg);
            const float hnew = so * tanhf(creg);
            hglob[((size_t)(wb * NXCD + xcd) * NB + b_) * Hh + gj] = hnew;
        }
        __syncthreads();   // compiler emits vmcnt(0) before s_barrier: h in L2

        // ---- D: single-arrival barrier (1 agent-scope RMW per block) ----
        if (tid == 0)
            __hip_atomic_fetch_add(mycnt, 1, __ATOMIC_RELAXED,
                                   __HIP_MEMORY_SCOPE_AGENT);

        // ---- E: wave 0 polls ONE word (same-address lanes coalesce) ----
        if (wv == 0) {
            const int target = (t + 1) * BPX;
            int v = __hip_atomic_load(mycnt, __ATOMIC_RELAXED,
                                      __HIP_MEMORY_SCOPE_AGENT);
            while (v < target) {
                __builtin_amdgcn_s_sleep(4);
                v = __hip_atomic_load(mycnt, __ATOMIC_RELAXED,
                                      __HIP_MEMORY_SCOPE_AGENT);
            }
            // invalidate vector L1 only; peers' h is in our shared XCD L2
            asm volatile("buffer_inv\n\ts_waitcnt vmcnt(0)" ::: "memory");

            if (owner) {
                const float4* hr = h4 + (size_t)(wb * NXCD + xcd) * 2048
                                      + rank * 128 + lane * 2;
                const float4 hA = hr[0], hB = hr[1];
                const float4* wt4 = (const float4*)w_t;
                const float4* wf4 = (const float4*)w_fc;
                float r[12];
                r[0] = dot4(hA, wt4[lane * 2])       + dot4(hB, wt4[lane * 2 + 1]);
                r[1] = dot4(hA, wt4[128 + lane * 2]) + dot4(hB, wt4[128 + lane * 2 + 1]);
                #pragma unroll
                for (int c = 0; c < Cc; ++c)
                    r[2 + c] = dot4(hA, wf4[c * 128 + lane * 2])
                             + dot4(hB, wf4[c * 128 + lane * 2 + 1]);
                #pragma unroll
                for (int m = 1; m <= 32; m <<= 1)
                    #pragma unroll
                    for (int k2 = 0; k2 < 12; ++k2)
                        r[k2] += __shfl_xor(r[k2], m, 64);

                if (lane == 0) {
                    const float a = r[0], b2 = r[1];
                    float* po = out + ((size_t)gb_own * Tt + t) * Cc;
                    #pragma unroll
                    for (int c = 0; c < Cc; ++c) {
                        const float hw = r[2 + c];
                        po[c] = hw + a * S1w[c] + S2w[c] + bfc_r[c];
                        S1w[c] += hw;
                        S2w[c] += b2 * hw;
                    }
                }
            }
        }
        __syncthreads();   // whole block proceeds only after poll + owner phase
    }
}

extern "C" void kernel_launch(void* const* d_in, const int* in_sizes, int n_in,
                              void* d_out, int out_size, void* d_ws, size_t ws_size,
                              hipStream_t stream)
{
    const float* xp  = (const float*)d_in[0];
    const float* wih = (const float*)d_in[1];
    const float* whh = (const float*)d_in[2];
    const float* bih = (const float*)d_in[3];
    const float* bhh = (const float*)d_in[4];
    const float* wt  = (const float*)d_in[5];
    const float* wfc = (const float*)d_in[6];
    const float* bfc = (const float*)d_in[7];
    float* outp = (float*)d_out;
    float* ws   = (float*)d_ws;

    // zero barrier + rank counters each call (graph-capturable)
    (void)hipMemsetAsync(d_ws, 0, 4096, stream);

    hipLaunchKernelGGL(lstm_fused, dim3(GRID), dim3(THREADS), 0, stream,
                       xp, wih, whh, bih, bhh, wt, wfc, bfc, outp, ws);
}

// Round 7
// 46886.246 us; speedup vs baseline: 1.0261x; 1.0261x over previous
//
#include <hip/hip_runtime.h>
#include <math.h>

static constexpr int Bz = 128;
static constexpr int Tt = 1024;
static constexpr int Hh = 512;
static constexpr int Cc = 10;

static constexpr int NXCD = 8;       // XCDs; each runs an independent group
static constexpr int BPX  = 32;      // blocks (CUs) per XCD
static constexpr int UPB  = 16;      // hidden units per block (64 gate rows)
static constexpr int NB   = 16;      // batch rows per XCD (8*16 = 128)
static constexpr int THREADS = 256;
static constexpr int GRID = 256;     // 1 block per CU (LDS-forced)

// ws bytes: [0,1024)   barrier cnt[8], stride 32 ints (one line per XCD)
//           [1024,2048) rank counters[8], stride 32 ints
//           [4096,...)  h[2][8][16][512] fp32
static constexpr size_t WS_H_F  = 1024;   // float offset of h
static constexpr size_t WS_H_F4 = 256;    // float4 offset of h

__device__ __forceinline__ float dot4(float4 a, float4 b) {
    return a.x * b.x + a.y * b.y + a.z * b.z + a.w * b.w;
}

__global__ __launch_bounds__(THREADS, 1)
void lstm_fused(const float* __restrict__ x,
                const float* __restrict__ w_ih,
                const float* __restrict__ w_hh,
                const float* __restrict__ b_ih,
                const float* __restrict__ b_hh,
                const float* __restrict__ w_t,
                const float* __restrict__ w_fc,
                const float* __restrict__ b_fc,
                float* __restrict__ out,
                float* __restrict__ ws)
{
    const int tid  = threadIdx.x;
    const int lane = tid & 63;
    const int wv   = tid >> 6;        // wave id = gate id in GEMM
    const int ks   = lane & 15;       // K-slice lane
    const int bg   = lane >> 4;       // batch group (4 rows each)

    int*    bar      = (int*)ws;            // [xcd*32]
    int*    counters = (int*)ws + 256;      // [xcd*32]
    float*  hglob    = ws + WS_H_F;
    float4* h4       = (float4*)ws + WS_H_F4;

    // LDS: w slice 128 KB + h tile 32 KB = exactly 160 KiB (gbuf aliases hls)
    __shared__ float4 wls[64 * 128];
    __shared__ float4 hls[16 * 128];
    float* gbuf = (float*)hls;        // 64 x 17 floats, used only post-GEMM

    // ---- discover physical XCD, claim a rank (exchange aliased into hls) ----
    int* xchg = (int*)hls;            // hls is dead until loop phase A
    if (tid == 0) {
        int xr;
        asm volatile("s_getreg_b32 %0, hwreg(20, 0, 32)" : "=s"(xr));
        const int xcd = xr & 7;
        xchg[0] = xcd;
        xchg[1] = atomicAdd(&counters[xcd * 32], 1) & 31;   // device-scope RMW
    }
    __syncthreads();
    const int xcd  = xchg[0];
    const int rank = xchg[1];
    __syncthreads();                  // everyone read before hls is reused
    int* mycnt = &bar[xcd * 32];

    // ---- preload w_hh slice: rows g*512 + rank*16 + j  ->  wls[g*16+j] ----
    {
        const float4* w4 = (const float4*)w_hh;
        #pragma unroll
        for (int g = 0; g < 4; ++g)
            #pragma unroll
            for (int n = 0; n < 8; ++n) {
                const int idx = n * 256 + tid;        // 0..2047
                const int j = idx >> 7, col = idx & 127;
                wls[(g * UPB + j) * 128 + col] =
                    w4[(size_t)(g * Hh + rank * UPB + j) * 128 + col];
            }
    }

    // ---- elementwise role: thread -> (u, b) ----
    const int u  = tid & 15;
    const int b_ = tid >> 4;                 // 0..15
    const int gj = rank * UPB + u;           // global hidden unit
    const int gb = xcd * NB + b_;            // global batch row
    float wih_r[4], bias_r[4];
    #pragma unroll
    for (int g = 0; g < 4; ++g) {
        wih_r[g]  = w_ih[g * Hh + gj];
        bias_r[g] = b_ih[g * Hh + gj] + b_hh[g * Hh + gj];
    }
    float creg = 0.0f;

    // ---- owner role: ranks 0..15 own batch row xcd*16+rank ----
    const bool owner = (rank < NB);
    const int  gb_own = xcd * NB + rank;
    float S1w[Cc], S2w[Cc], bfc_r[Cc];
    #pragma unroll
    for (int c = 0; c < Cc; ++c) { S1w[c] = 0.f; S2w[c] = 0.f; bfc_r[c] = b_fc[c]; }

    for (int t = 0; t < Tt; ++t) {
        const int rb = t & 1, wb = rb ^ 1;

        // ---- A: stage h_t (16 x 512) into LDS (XCD-L2-local, plain loads) ----
        if (t == 0) {
            const float4 z = make_float4(0.f, 0.f, 0.f, 0.f);
            #pragma unroll
            for (int n = 0; n < 8; ++n) hls[n * 256 + tid] = z;
        } else {
            const float4* src = h4 + (size_t)(rb * NXCD + xcd) * 2048;
            #pragma unroll
            for (int n = 0; n < 8; ++n) hls[n * 256 + tid] = src[n * 256 + tid];
        }
        __syncthreads();

        // ---- B: GEMM 64x16x512, wave = gate, 16x4 reg tile, K split 16 ----
        float acc[16][4];
        #pragma unroll
        for (int j = 0; j < 16; ++j)
            #pragma unroll
            for (int i = 0; i < 4; ++i) acc[j][i] = 0.f;

        #pragma unroll
        for (int q = 0; q < 8; ++q) {
            const int kq = ks + q * 16;
            float4 hv[4];
            #pragma unroll
            for (int i = 0; i < 4; ++i) hv[i] = hls[(bg * 4 + i) * 128 + kq];
            #pragma unroll
            for (int j2 = 0; j2 < 2; ++j2) {
                float4 wf[8];
                #pragma unroll
                for (int j = 0; j < 8; ++j)
                    wf[j] = wls[(wv * UPB + j2 * 8 + j) * 128 + kq];
                #pragma unroll
                for (int j = 0; j < 8; ++j)
                    #pragma unroll
                    for (int i = 0; i < 4; ++i)
                        acc[j2 * 8 + j][i] += wf[j].x * hv[i].x + wf[j].y * hv[i].y
                                            + wf[j].z * hv[i].z + wf[j].w * hv[i].w;
            }
        }
        #pragma unroll
        for (int m = 1; m <= 8; m <<= 1)
            #pragma unroll
            for (int j = 0; j < 16; ++j)
                #pragma unroll
                for (int i = 0; i < 4; ++i)
                    acc[j][i] += __shfl_xor(acc[j][i], m, 64);

        __syncthreads();          // all hls reads done before gbuf clobbers it
        if (ks == 0) {
            #pragma unroll
            for (int j = 0; j < 16; ++j)
                #pragma unroll
                for (int i = 0; i < 4; ++i)
                    gbuf[(wv * UPB + j) * 17 + (bg * 4 + i)] = acc[j][i];
        }
        __syncthreads();

        // ---- C: LSTM elementwise, write h_t+1 (plain store -> XCD L2) ----
        {
            const float xv = x[(size_t)gb * Tt + t];
            const float gi = gbuf[(0 * UPB + u) * 17 + b_] + xv * wih_r[0] + bias_r[0];
            const float gf = gbuf[(1 * UPB + u) * 17 + b_] + xv * wih_r[1] + bias_r[1];
            const float gg = gbuf[(2 * UPB + u) * 17 + b_] + xv * wih_r[2] + bias_r[2];
            const float go = gbuf[(3 * UPB + u) * 17 + b_] + xv * wih_r[3] + bias_r[3];
            const float si = 1.f / (1.f + expf(-gi));
            const float sf = 1.f / (1.f + expf(-gf));
            const float so = 1.f / (1.f + expf(-go));
            creg = sf * creg + si * tanhf(gg);
            const float hnew = so * tanhf(creg);
            hglob[((size_t)(wb * NXCD + xcd) * NB + b_) * Hh + gj] = hnew;
        }
        __syncthreads();   // compiler emits vmcnt(0) before s_barrier: h in L2

        // ---- D+E: ONE arrival RMW and ONE polling lane per block ----
        if (tid == 0) {
            __hip_atomic_fetch_add(mycnt, 1, __ATOMIC_RELAXED,
                                   __HIP_MEMORY_SCOPE_AGENT);
            const int target = (t + 1) * BPX;
            int v = __hip_atomic_load(mycnt, __ATOMIC_RELAXED,
                                      __HIP_MEMORY_SCOPE_AGENT);
            while (v < target) {
                __builtin_amdgcn_s_sleep(8);
                v = __hip_atomic_load(mycnt, __ATOMIC_RELAXED,
                                      __HIP_MEMORY_SCOPE_AGENT);
            }
            // invalidate vector L1 only; peers' h is in our shared XCD L2
            asm volatile("buffer_inv\n\ts_waitcnt vmcnt(0)" ::: "memory");
        }
        __syncthreads();   // whole block released; L1 inv done before any load

        // ---- F: owner emits this step's 10 output channels ----
        if (wv == 0 && owner) {
            const float4* hr = h4 + (size_t)(wb * NXCD + xcd) * 2048
                                  + rank * 128 + lane * 2;
            const float4 hA = hr[0], hB = hr[1];
            const float4* wt4 = (const float4*)w_t;
            const float4* wf4 = (const float4*)w_fc;
            float r[12];
            r[0] = dot4(hA, wt4[lane * 2])       + dot4(hB, wt4[lane * 2 + 1]);
            r[1] = dot4(hA, wt4[128 + lane * 2]) + dot4(hB, wt4[128 + lane * 2 + 1]);
            #pragma unroll
            for (int c = 0; c < Cc; ++c)
                r[2 + c] = dot4(hA, wf4[c * 128 + lane * 2])
                         + dot4(hB, wf4[c * 128 + lane * 2 + 1]);
            #pragma unroll
            for (int m = 1; m <= 32; m <<= 1)
                #pragma unroll
                for (int k2 = 0; k2 < 12; ++k2)
                    r[k2] += __shfl_xor(r[k2], m, 64);

            if (lane == 0) {
                const float a = r[0], b2 = r[1];
                float* po = out + ((size_t)gb_own * Tt + t) * Cc;
                #pragma unroll
                for (int c = 0; c < Cc; ++c) {
                    const float hw = r[2 + c];
                    po[c] = hw + a * S1w[c] + S2w[c] + bfc_r[c];
                    S1w[c] += hw;
                    S2w[c] += b2 * hw;
                }
            }
        }
        __syncthreads();   // owner phase done before hls/gbuf reuse next step
    }
}

extern "C" void kernel_launch(void* const* d_in, const int* in_sizes, int n_in,
                              void* d_out, int out_size, void* d_ws, size_t ws_size,
                              hipStream_t stream)
{
    const float* xp  = (const float*)d_in[0];
    const float* wih = (const float*)d_in[1];
    const float* whh = (const float*)d_in[2];
    const float* bih = (const float*)d_in[3];
    const float* bhh = (const float*)d_in[4];
    const float* wt  = (const float*)d_in[5];
    const float* wfc = (const float*)d_in[6];
    const float* bfc = (const float*)d_in[7];
    float* outp = (float*)d_out;
    float* ws   = (float*)d_ws;

    // zero barrier + rank counters each call (graph-capturable)
    (void)hipMemsetAsync(d_ws, 0, 4096, stream);

    hipLaunchKernelGGL(lstm_fused, dim3(GRID), dim3(THREADS), 0, stream,
                       xp, wih, whh, bih, bhh, wt, wfc, bfc, outp, ws);
}

// Round 8
// 12231.855 us; speedup vs baseline: 3.9330x; 3.8331x over previous
//
#include <hip/hip_runtime.h>
#include <math.h>

static constexpr int Bz = 128;
static constexpr int Tt = 1024;
static constexpr int Hh = 512;
static constexpr int Cc = 10;

static constexpr int NXCD = 8;       // XCDs; each runs an independent group
static constexpr int BPX  = 32;      // blocks (CUs) per XCD
static constexpr int UPB  = 16;      // hidden units per block (64 gate rows)
static constexpr int NB   = 16;      // batch rows per XCD (8*16 = 128)
static constexpr int THREADS = 256;
static constexpr int GRID = 256;     // 1 block per CU (LDS-forced)

// ws bytes: [0,1024)   barrier cnt[8], stride 32 ints (one line per XCD)
//           [1024,2048) rank counters[8], stride 32 ints
//           [4096,...)  h[2][8][16][512] fp32
static constexpr size_t WS_H_F  = 1024;   // float offset of h
static constexpr size_t WS_H_F4 = 256;    // float4 offset of h

__device__ __forceinline__ float dot4(float4 a, float4 b) {
    return a.x * b.x + a.y * b.y + a.z * b.z + a.w * b.w;
}

__global__ __launch_bounds__(THREADS, 1)
void lstm_fused(const float* __restrict__ x,
                const float* __restrict__ w_ih,
                const float* __restrict__ w_hh,
                const float* __restrict__ b_ih,
                const float* __restrict__ b_hh,
                const float* __restrict__ w_t,
                const float* __restrict__ w_fc,
                const float* __restrict__ b_fc,
                float* __restrict__ out,
                float* __restrict__ ws)
{
    const int tid  = threadIdx.x;
    const int lane = tid & 63;
    const int wv   = tid >> 6;        // wave id = gate id in GEMM
    // GEMM lane decomposition: K-split 8, tile 8 rows x 4 batches
    const int ks   = lane & 7;         // K-slice lane (8-way)
    const int rh   = (lane >> 3) & 1;  // row half (8 rows each)
    const int bq   = lane >> 4;        // batch quarter (4 batches each)

    int*    bar      = (int*)ws;            // [xcd*32]
    int*    counters = (int*)ws + 256;      // [xcd*32]
    float*  hglob    = ws + WS_H_F;
    float4* h4       = (float4*)ws + WS_H_F4;

    // LDS: w slice 128 KB + h tile 32 KB = exactly 160 KiB (gbuf aliases hls)
    __shared__ float4 wls[64 * 128];
    __shared__ float4 hls[16 * 128];
    float* gbuf = (float*)hls;        // 64 x 20 floats, used only post-GEMM

    // ---- discover physical XCD, claim a rank (exchange aliased into hls) ----
    int* xchg = (int*)hls;            // hls is dead until loop phase A
    if (tid == 0) {
        int xr;
        asm volatile("s_getreg_b32 %0, hwreg(20, 0, 32)" : "=s"(xr));
        const int xcd = xr & 7;
        xchg[0] = xcd;
        xchg[1] = atomicAdd(&counters[xcd * 32], 1) & 31;   // device-scope RMW
    }
    __syncthreads();
    const int xcd  = xchg[0];
    const int rank = xchg[1];
    __syncthreads();                  // everyone read before hls is reused
    int* mycnt = &bar[xcd * 32];

    // ---- preload w_hh slice: rows g*512 + rank*16 + j  ->  wls[g*16+j] ----
    {
        const float4* w4 = (const float4*)w_hh;
        #pragma unroll
        for (int g = 0; g < 4; ++g)
            #pragma unroll
            for (int n = 0; n < 8; ++n) {
                const int idx = n * 256 + tid;        // 0..2047
                const int j = idx >> 7, col = idx & 127;
                wls[(g * UPB + j) * 128 + col] =
                    w4[(size_t)(g * Hh + rank * UPB + j) * 128 + col];
            }
    }

    // ---- elementwise role: thread -> (u, b) ----
    const int u  = tid & 15;
    const int b_ = tid >> 4;                 // 0..15
    const int gj = rank * UPB + u;           // global hidden unit
    const int gb = xcd * NB + b_;            // global batch row
    float wih_r[4], bias_r[4];
    #pragma unroll
    for (int g = 0; g < 4; ++g) {
        wih_r[g]  = w_ih[g * Hh + gj];
        bias_r[g] = b_ih[g * Hh + gj] + b_hh[g * Hh + gj];
    }
    float creg = 0.0f;

    // ---- owner role: ranks 0..15 own batch row xcd*16+rank ----
    const bool owner = (rank < NB);
    const int  gb_own = xcd * NB + rank;
    float S1w[Cc], S2w[Cc], bfc_r[Cc];
    #pragma unroll
    for (int c = 0; c < Cc; ++c) { S1w[c] = 0.f; S2w[c] = 0.f; bfc_r[c] = b_fc[c]; }

    // GEMM row/col bases for this lane
    const int wrow0 = wv * UPB + rh * 8;     // first of 8 w rows
    const int hcol0 = bq * 4;                // first of 4 batches

    for (int t = 0; t < Tt; ++t) {
        const int rb = t & 1, wb = rb ^ 1;

        // ---- A: stage h_t (16 x 512) into LDS (XCD-L2-local, plain loads) ----
        if (t == 0) {
            const float4 z = make_float4(0.f, 0.f, 0.f, 0.f);
            #pragma unroll
            for (int n = 0; n < 8; ++n) hls[n * 256 + tid] = z;
        } else {
            const float4* src = h4 + (size_t)(rb * NXCD + xcd) * 2048;
            #pragma unroll
            for (int n = 0; n < 8; ++n) hls[n * 256 + tid] = src[n * 256 + tid];
        }
        __syncthreads();

        // ---- B: GEMM 64x16x512; 8x4 reg tile, K split 8 ways ----
        float acc[8][4];
        #pragma unroll
        for (int j = 0; j < 8; ++j)
            #pragma unroll
            for (int i = 0; i < 4; ++i) acc[j][i] = 0.f;

        #pragma unroll 2
        for (int c = 0; c < 16; ++c) {
            const int g0 = c * 8 + ks;       // float4 granule within row
            float4 hv[4];
            #pragma unroll
            for (int i = 0; i < 4; ++i) hv[i] = hls[(hcol0 + i) * 128 + g0];
            #pragma unroll
            for (int j = 0; j < 8; ++j) {
                const float4 wf = wls[(wrow0 + j) * 128 + g0];
                #pragma unroll
                for (int i = 0; i < 4; ++i)
                    acc[j][i] += wf.x * hv[i].x + wf.y * hv[i].y
                               + wf.z * hv[i].z + wf.w * hv[i].w;
            }
        }
        #pragma unroll
        for (int m = 1; m <= 4; m <<= 1)
            #pragma unroll
            for (int j = 0; j < 8; ++j)
                #pragma unroll
                for (int i = 0; i < 4; ++i)
                    acc[j][i] += __shfl_xor(acc[j][i], m, 64);

        __syncthreads();          // all hls reads done before gbuf clobbers it
        if (ks == 0) {
            #pragma unroll
            for (int j = 0; j < 8; ++j)
                *(float4*)&gbuf[(wrow0 + j) * 20 + hcol0] =
                    make_float4(acc[j][0], acc[j][1], acc[j][2], acc[j][3]);
        }
        __syncthreads();

        // ---- C: LSTM elementwise, write h_t+1 (plain store -> XCD L2) ----
        {
            const float xv = x[(size_t)gb * Tt + t];
            const float gi = gbuf[(0 * UPB + u) * 20 + b_] + xv * wih_r[0] + bias_r[0];
            const float gf = gbuf[(1 * UPB + u) * 20 + b_] + xv * wih_r[1] + bias_r[1];
            const float gg = gbuf[(2 * UPB + u) * 20 + b_] + xv * wih_r[2] + bias_r[2];
            const float go = gbuf[(3 * UPB + u) * 20 + b_] + xv * wih_r[3] + bias_r[3];
            const float si = 1.f / (1.f + expf(-gi));
            const float sf = 1.f / (1.f + expf(-gf));
            const float so = 1.f / (1.f + expf(-go));
            creg = sf * creg + si * tanhf(gg);
            const float hnew = so * tanhf(creg);
            hglob[((size_t)(wb * NXCD + xcd) * NB + b_) * Hh + gj] = hnew;
        }
        __syncthreads();   // compiler emits vmcnt(0) before s_barrier: h in L2

        // ---- D+E: ONE arrival RMW and ONE polling lane per block ----
        if (tid == 0) {
            __hip_atomic_fetch_add(mycnt, 1, __ATOMIC_RELAXED,
                                   __HIP_MEMORY_SCOPE_AGENT);
            const int target = (t + 1) * BPX;
            int v = __hip_atomic_load(mycnt, __ATOMIC_RELAXED,
                                      __HIP_MEMORY_SCOPE_AGENT);
            while (v < target) {
                __builtin_amdgcn_s_sleep(8);
                v = __hip_atomic_load(mycnt, __ATOMIC_RELAXED,
                                      __HIP_MEMORY_SCOPE_AGENT);
            }
            // invalidate vector L1 only; peers' h is in our shared XCD L2
            asm volatile("buffer_inv\n\ts_waitcnt vmcnt(0)" ::: "memory");
        }
        __syncthreads();   // whole block released; L1 inv done before any load

        // ---- F: owner emits this step's 10 output channels ----
        if (wv == 0 && owner) {
            const float4* hr = h4 + (size_t)(wb * NXCD + xcd) * 2048
                                  + rank * 128 + lane * 2;
            const float4 hA = hr[0], hB = hr[1];
            const float4* wt4 = (const float4*)w_t;
            const float4* wf4 = (const float4*)w_fc;
            float r[12];
            r[0] = dot4(hA, wt4[lane * 2])       + dot4(hB, wt4[lane * 2 + 1]);
            r[1] = dot4(hA, wt4[128 + lane * 2]) + dot4(hB, wt4[128 + lane * 2 + 1]);
            #pragma unroll
            for (int c = 0; c < Cc; ++c)
                r[2 + c] = dot4(hA, wf4[c * 128 + lane * 2])
                         + dot4(hB, wf4[c * 128 + lane * 2 + 1]);
            #pragma unroll
            for (int m = 1; m <= 32; m <<= 1)
                #pragma unroll
                for (int k2 = 0; k2 < 12; ++k2)
                    r[k2] += __shfl_xor(r[k2], m, 64);

            if (lane == 0) {
                const float a = r[0], b2 = r[1];
                float* po = out + ((size_t)gb_own * Tt + t) * Cc;
                #pragma unroll
                for (int c = 0; c < Cc; ++c) {
                    const float hw = r[2 + c];
                    po[c] = hw + a * S1w[c] + S2w[c] + bfc_r[c];
                    S1w[c] += hw;
                    S2w[c] += b2 * hw;
                }
            }
        }
        __syncthreads();   // owner phase done before hls/gbuf reuse next step
    }
}

extern "C" void kernel_launch(void* const* d_in, const int* in_sizes, int n_in,
                              void* d_out, int out_size, void* d_ws, size_t ws_size,
                              hipStream_t stream)
{
    const float* xp  = (const float*)d_in[0];
    const float* wih = (const float*)d_in[1];
    const float* whh = (const float*)d_in[2];
    const float* bih = (const float*)d_in[3];
    const float* bhh = (const float*)d_in[4];
    const float* wt  = (const float*)d_in[5];
    const float* wfc = (const float*)d_in[6];
    const float* bfc = (const float*)d_in[7];
    float* outp = (float*)d_out;
    float* ws   = (float*)d_ws;

    // zero barrier + rank counters each call (graph-capturable)
    (void)hipMemsetAsync(d_ws, 0, 4096, stream);

    hipLaunchKernelGGL(lstm_fused, dim3(GRID), dim3(THREADS), 0, stream,
                       xp, wih, whh, bih, bhh, wt, wfc, bfc, outp, ws);
}

// Round 9
// 4774.227 us; speedup vs baseline: 10.0766x; 2.5621x over previous
//
#include <hip/hip_runtime.h>
#include <math.h>

typedef __attribute__((ext_vector_type(8))) short bf16x8;   // 8 bf16 (4 VGPR)
typedef __attribute__((ext_vector_type(4))) float f32x4;    // MFMA C/D

static constexpr int Tt = 1024;
static constexpr int Hh = 512;
static constexpr int Cc = 10;

static constexpr int NXCD = 8;       // XCDs; each runs an independent group
static constexpr int BPX  = 32;      // blocks (CUs) per XCD
static constexpr int UPB  = 16;      // hidden units per block (64 gate rows)
static constexpr int NB   = 16;      // batch rows per XCD (8*16 = 128)
static constexpr int THREADS = 256;
static constexpr int GRID = 256;     // 1 block per CU (LDS-forced)

// ws bytes: [0,1024) barrier cnt[8] stride-32-int | [1024,2048) rank counters
//           [4096, +32KB) h_hi[2][8][16][512] bf16 | then h_lo same size
static constexpr size_t WS_HHI_B = 4096;
static constexpr size_t WS_HLO_B = 4096 + 32768;

__device__ __forceinline__ unsigned short f2bf(float f) {
    unsigned u = __builtin_bit_cast(unsigned, f);
    return (unsigned short)((u + 0x7FFFu + ((u >> 16) & 1u)) >> 16);   // RNE
}
__device__ __forceinline__ float bf2f(unsigned short h) {
    unsigned u = ((unsigned)h) << 16;
    return __builtin_bit_cast(float, u);
}
__device__ __forceinline__ float dot4(float4 a, float4 b) {
    return a.x * b.x + a.y * b.y + a.z * b.z + a.w * b.w;
}

__global__ __launch_bounds__(THREADS, 1)
void lstm_fused(const float* __restrict__ x,
                const float* __restrict__ w_ih,
                const float* __restrict__ w_hh,
                const float* __restrict__ b_ih,
                const float* __restrict__ b_hh,
                const float* __restrict__ w_t,
                const float* __restrict__ w_fc,
                const float* __restrict__ b_fc,
                float* __restrict__ out,
                float* __restrict__ ws)
{
    const int tid  = threadIdx.x;
    const int lane = tid & 63;
    const int wv   = tid >> 6;        // wave id = gate id (MFMA row-tile)

    int* bar      = (int*)ws;               // [xcd*32]
    int* counters = (int*)ws + 256;         // [xcd*32]
    unsigned short* hg_hi = (unsigned short*)((char*)ws + WS_HHI_B);
    unsigned short* hg_lo = (unsigned short*)((char*)ws + WS_HLO_B);

    // LDS: Whi 64K + Wlo 64K + hhi 16K + hlo 16K = exactly 160 KiB
    __shared__ __align__(16) short wls_hi[64 * 512];
    __shared__ __align__(16) short wls_lo[64 * 512];
    __shared__ __align__(16) short hhi_ls[16 * 512];
    __shared__ __align__(16) short hlo_ls[16 * 512];
    float* gbuf = (float*)hhi_ls;     // 64 x 20 fp32 (5 KB), post-GEMM only
    int*   xchg = (int*)hlo_ls;       // init-time only

    // ---- discover physical XCD, claim a rank ----
    if (tid == 0) {
        int xr;
        asm volatile("s_getreg_b32 %0, hwreg(20, 0, 32)" : "=s"(xr));
        const int xcd = xr & 7;
        xchg[0] = xcd;
        xchg[1] = atomicAdd(&counters[xcd * 32], 1) & 31;
    }
    __syncthreads();
    const int xcd  = xchg[0];
    const int rank = xchg[1];
    __syncthreads();                  // reads done before hlo_ls reuse
    int* mycnt = &bar[xcd * 32];

    // ---- preload + split w_hh slice into bf16 hi/lo, XOR-swizzled ----
    {
        #pragma unroll
        for (int it = 0; it < 16; ++it) {
            const int idx = it * 256 + tid;        // [0,4096): lr(64) x kg(64)
            const int lr = idx >> 6, kg = idx & 63;
            const int grow = (lr >> 4) * Hh + rank * UPB + (lr & 15);
            const float4* src = (const float4*)(w_hh + (size_t)grow * Hh + kg * 8);
            const float4 f0 = src[0], f1 = src[1];
            const float f[8] = { f0.x, f0.y, f0.z, f0.w, f1.x, f1.y, f1.z, f1.w };
            bf16x8 vhi, vlo;
            #pragma unroll
            for (int j = 0; j < 8; ++j) {
                const unsigned short h = f2bf(f[j]);
                vhi[j] = (short)h;
                vlo[j] = (short)f2bf(f[j] - bf2f(h));
            }
            const int off = (lr * 1024 + kg * 16) ^ ((lr & 7) << 4);
            *(bf16x8*)((char*)wls_hi + off) = vhi;
            *(bf16x8*)((char*)wls_lo + off) = vlo;
        }
    }

    // ---- elementwise role: thread -> (u, b) ----
    const int u  = tid & 15;
    const int b_ = tid >> 4;                 // 0..15
    const int gj = rank * UPB + u;           // global hidden unit
    const int gb = xcd * NB + b_;            // global batch row
    float wih_r[4], bias_r[4];
    #pragma unroll
    for (int g = 0; g < 4; ++g) {
        wih_r[g]  = w_ih[g * Hh + gj];
        bias_r[g] = b_ih[g * Hh + gj] + b_hh[g * Hh + gj];
    }
    float creg = 0.0f;

    // ---- owner role: ranks 0..15 own batch row xcd*16+rank ----
    const bool owner = (rank < NB);
    const int  gb_own = xcd * NB + rank;
    float S1w[Cc], S2w[Cc], bfc_r[Cc];
    #pragma unroll
    for (int c = 0; c < Cc; ++c) { S1w[c] = 0.f; S2w[c] = 0.f; bfc_r[c] = b_fc[c]; }

    // MFMA fragment addressing (A = W rows of gate wv, B = h batches)
    const int arow  = wv * 16 + (lane & 15);
    const int aoff0 = arow * 1024 + ((lane >> 4) << 4);
    const int boff0 = (lane & 15) * 1024 + ((lane >> 4) << 4);
    const int xmask = (lane & 7) << 4;

    for (int t = 0; t < Tt; ++t) {
        const int rb = t & 1, wb = rb ^ 1;
        const float xv = x[(size_t)gb * Tt + t];   // issued early, used in C

        // ---- A: stage h_t hi/lo (16 x 512 bf16 each) into swizzled LDS ----
        if (t == 0) {
            const bf16x8 z = { 0, 0, 0, 0, 0, 0, 0, 0 };
            #pragma unroll
            for (int it = 0; it < 4; ++it) {
                const int idx = it * 256 + tid;
                const int row = idx >> 6, kg = idx & 63;
                const int off = (row * 1024 + kg * 16) ^ ((row & 7) << 4);
                *(bf16x8*)((char*)hhi_ls + off) = z;
                *(bf16x8*)((char*)hlo_ls + off) = z;
            }
        } else {
            const bf16x8* shi = (const bf16x8*)(hg_hi + (size_t)(rb * NXCD + xcd) * NB * Hh);
            const bf16x8* slo = (const bf16x8*)(hg_lo + (size_t)(rb * NXCD + xcd) * NB * Hh);
            #pragma unroll
            for (int it = 0; it < 4; ++it) {
                const int idx = it * 256 + tid;        // row*64 + kg
                const int row = idx >> 6, kg = idx & 63;
                const bf16x8 vhi = shi[idx];
                const bf16x8 vlo = slo[idx];
                const int off = (row * 1024 + kg * 16) ^ ((row & 7) << 4);
                *(bf16x8*)((char*)hhi_ls + off) = vhi;
                *(bf16x8*)((char*)hlo_ls + off) = vlo;
            }
        }
        __syncthreads();

        // ---- B: gates GEMM 64x16x512 via 3-pass split-bf16 MFMA ----
        f32x4 acc0 = { 0.f, 0.f, 0.f, 0.f };
        f32x4 acc1 = { 0.f, 0.f, 0.f, 0.f };
        f32x4 acc2 = { 0.f, 0.f, 0.f, 0.f };
        #pragma unroll
        for (int kk = 0; kk < 16; ++kk) {
            const int ao = (aoff0 + kk * 64) ^ xmask;
            const int bo = (boff0 + kk * 64) ^ xmask;
            const bf16x8 ahi = *(const bf16x8*)((const char*)wls_hi + ao);
            const bf16x8 alo = *(const bf16x8*)((const char*)wls_lo + ao);
            const bf16x8 bhi = *(const bf16x8*)((const char*)hhi_ls + bo);
            const bf16x8 blo = *(const bf16x8*)((const char*)hlo_ls + bo);
            acc0 = __builtin_amdgcn_mfma_f32_16x16x32_bf16(ahi, bhi, acc0, 0, 0, 0);
            acc1 = __builtin_amdgcn_mfma_f32_16x16x32_bf16(ahi, blo, acc1, 0, 0, 0);
            acc2 = __builtin_amdgcn_mfma_f32_16x16x32_bf16(alo, bhi, acc2, 0, 0, 0);
        }
        __syncthreads();          // all LDS frag reads done before gbuf aliases

        // C/D layout: col=lane&15 (batch), row=(lane>>4)*4+reg (unit in tile)
        {
            const int unit0 = (lane >> 4) * 4;
            const int batch = lane & 15;
            #pragma unroll
            for (int r = 0; r < 4; ++r)
                gbuf[(wv * 16 + unit0 + r) * 20 + batch] = acc0[r] + acc1[r] + acc2[r];
        }
        __syncthreads();

        // ---- C: LSTM elementwise, write h hi/lo (plain stores -> XCD L2) ----
        {
            const float gi = gbuf[(0 * UPB + u) * 20 + b_] + xv * wih_r[0] + bias_r[0];
            const float gf = gbuf[(1 * UPB + u) * 20 + b_] + xv * wih_r[1] + bias_r[1];
            const float gg = gbuf[(2 * UPB + u) * 20 + b_] + xv * wih_r[2] + bias_r[2];
            const float go = gbuf[(3 * UPB + u) * 20 + b_] + xv * wih_r[3] + bias_r[3];
            const float si = 1.f / (1.f + expf(-gi));
            const float sf = 1.f / (1.f + expf(-gf));
            const float so = 1.f / (1.f + expf(-go));
            creg = sf * creg + si * tanhf(gg);
            const float hnew = so * tanhf(creg);
            const unsigned short hb = f2bf(hnew);
            const unsigned short lb = f2bf(hnew - bf2f(hb));
            const size_t hoff = ((size_t)(wb * NXCD + xcd) * NB + b_) * Hh + gj;
            hg_hi[hoff] = hb;
            hg_lo[hoff] = lb;
        }
        __syncthreads();   // vmcnt(0) drained before barrier: h visible in L2

        // ---- D+E: one arrival RMW + one polling lane per block ----
        if (tid == 0) {
            __hip_atomic_fetch_add(mycnt, 1, __ATOMIC_RELAXED,
                                   __HIP_MEMORY_SCOPE_AGENT);
            const int target = (t + 1) * BPX;
            int v = __hip_atomic_load(mycnt, __ATOMIC_RELAXED,
                                      __HIP_MEMORY_SCOPE_AGENT);
            while (v < target) {
                __builtin_amdgcn_s_sleep(2);
                v = __hip_atomic_load(mycnt, __ATOMIC_RELAXED,
                                      __HIP_MEMORY_SCOPE_AGENT);
            }
            asm volatile("buffer_inv\n\ts_waitcnt vmcnt(0)" ::: "memory");
        }
        __syncthreads();   // block released; L1 invalidated before any h load

        // ---- F: owner emits this step's 10 output channels ----
        if (wv == 0 && owner) {
            const size_t rbase = ((size_t)(wb * NXCD + xcd) * NB + rank) * Hh + lane * 8;
            const bf16x8 vh = *(const bf16x8*)(hg_hi + rbase);
            const bf16x8 vl = *(const bf16x8*)(hg_lo + rbase);
            float f[8];
            #pragma unroll
            for (int j = 0; j < 8; ++j)
                f[j] = bf2f((unsigned short)vh[j]) + bf2f((unsigned short)vl[j]);
            const float4 hA = make_float4(f[0], f[1], f[2], f[3]);
            const float4 hB = make_float4(f[4], f[5], f[6], f[7]);
            const float4* wt4 = (const float4*)w_t;
            const float4* wf4 = (const float4*)w_fc;
            float r[12];
            r[0] = dot4(hA, wt4[lane * 2])       + dot4(hB, wt4[lane * 2 + 1]);
            r[1] = dot4(hA, wt4[128 + lane * 2]) + dot4(hB, wt4[128 + lane * 2 + 1]);
            #pragma unroll
            for (int c = 0; c < Cc; ++c)
                r[2 + c] = dot4(hA, wf4[c * 128 + lane * 2])
                         + dot4(hB, wf4[c * 128 + lane * 2 + 1]);
            #pragma unroll
            for (int m = 1; m <= 32; m <<= 1)
                #pragma unroll
                for (int k2 = 0; k2 < 12; ++k2)
                    r[k2] += __shfl_xor(r[k2], m, 64);

            if (lane == 0) {
                const float a = r[0], b2 = r[1];
                float* po = out + ((size_t)gb_own * Tt + t) * Cc;
                #pragma unroll
                for (int c = 0; c < Cc; ++c) {
                    const float hw = r[2 + c];
                    po[c] = hw + a * S1w[c] + S2w[c] + bfc_r[c];
                    S1w[c] += hw;
                    S2w[c] += b2 * hw;
                }
            }
        }
        __syncthreads();   // owner done before next step reuses hhi/hlo LDS
    }
}

extern "C" void kernel_launch(void* const* d_in, const int* in_sizes, int n_in,
                              void* d_out, int out_size, void* d_ws, size_t ws_size,
                              hipStream_t stream)
{
    const float* xp  = (const float*)d_in[0];
    const float* wih = (const float*)d_in[1];
    const float* whh = (const float*)d_in[2];
    const float* bih = (const float*)d_in[3];
    const float* bhh = (const float*)d_in[4];
    const float* wt  = (const float*)d_in[5];
    const float* wfc = (const float*)d_in[6];
    const float* bfc = (const float*)d_in[7];
    float* outp = (float*)d_out;
    float* ws   = (float*)d_ws;

    // zero barrier + rank counters each call (graph-capturable)
    (void)hipMemsetAsync(d_ws, 0, 4096, stream);

    hipLaunchKernelGGL(lstm_fused, dim3(GRID), dim3(THREADS), 0, stream,
                       xp, wih, whh, bih, bhh, wt, wfc, bfc, outp, ws);
}

// Round 10
// 4423.992 us; speedup vs baseline: 10.8743x; 1.0792x over previous
//
#include <hip/hip_runtime.h>
#include <math.h>

typedef __attribute__((ext_vector_type(8))) short bf16x8;   // 8 bf16 (4 VGPR)
typedef __attribute__((ext_vector_type(4))) float f32x4;    // MFMA C/D

static constexpr int Tt = 1024;
static constexpr int Hh = 512;
static constexpr int Cc = 10;

static constexpr int NXCD = 8;       // XCDs; each runs an independent group
static constexpr int BPX  = 32;      // blocks (CUs) per XCD
static constexpr int UPB  = 16;      // hidden units per block (64 gate rows)
static constexpr int NB   = 16;      // batch rows per XCD (8*16 = 128)
static constexpr int THREADS = 256;
static constexpr int GRID = 256;     // 1 block per CU (LDS-forced)

// ws bytes: [0,1024) flags[8][32] int | [1024,2048) rank counters (init only)
//           [4096, +32KB) h_hi[2][8][16][512] bf16 | then h_lo same size
static constexpr size_t WS_HHI_B = 4096;
static constexpr size_t WS_HLO_B = 4096 + 32768;

__device__ __forceinline__ unsigned short f2bf(float f) {
    unsigned u = __builtin_bit_cast(unsigned, f);
    return (unsigned short)((u + 0x7FFFu + ((u >> 16) & 1u)) >> 16);   // RNE
}
__device__ __forceinline__ float bf2f(unsigned short h) {
    unsigned u = ((unsigned)h) << 16;
    return __builtin_bit_cast(float, u);
}
__device__ __forceinline__ float dot4(float4 a, float4 b) {
    return a.x * b.x + a.y * b.y + a.z * b.z + a.w * b.w;
}
// fast sigmoid/tanh via v_exp_f32 (2^x) + v_rcp_f32; saturate correctly at +-inf
__device__ __forceinline__ float fsig(float x) {
    const float e = __builtin_amdgcn_exp2f(x * -1.44269504f);
    return __builtin_amdgcn_rcpf(1.0f + e);
}
__device__ __forceinline__ float ftanh(float x) {
    const float e = __builtin_amdgcn_exp2f(x * -2.88539008f);   // x->-inf: e=+inf -> -1
    return 2.0f * __builtin_amdgcn_rcpf(1.0f + e) - 1.0f;
}

__global__ __launch_bounds__(THREADS, 1)
void lstm_fused(const float* __restrict__ x,
                const float* __restrict__ w_ih,
                const float* __restrict__ w_hh,
                const float* __restrict__ b_ih,
                const float* __restrict__ b_hh,
                const float* __restrict__ w_t,
                const float* __restrict__ w_fc,
                const float* __restrict__ b_fc,
                float* __restrict__ out,
                float* __restrict__ ws)
{
    const int tid  = threadIdx.x;
    const int lane = tid & 63;
    const int wv   = tid >> 6;        // wave id = gate id (MFMA row-tile)

    int* flags    = (int*)ws;               // [xcd*32 + rank]
    int* counters = (int*)ws + 256;         // init-time rank claim
    unsigned short* hg_hi = (unsigned short*)((char*)ws + WS_HHI_B);
    unsigned short* hg_lo = (unsigned short*)((char*)ws + WS_HLO_B);

    // LDS: Whi 64K + Wlo 64K + hhi 16K + hlo 16K = exactly 160 KiB
    __shared__ __align__(16) short wls_hi[64 * 512];
    __shared__ __align__(16) short wls_lo[64 * 512];
    __shared__ __align__(16) short hhi_ls[16 * 512];
    __shared__ __align__(16) short hlo_ls[16 * 512];
    float* gbuf = (float*)hhi_ls;     // 64 x 20 fp32 (5 KB), post-GEMM only
    int*   xchg = (int*)hlo_ls;       // init-time only

    // ---- discover physical XCD, claim a rank (one-time device-scope RMW) ----
    if (tid == 0) {
        int xr;
        asm volatile("s_getreg_b32 %0, hwreg(20, 0, 32)" : "=s"(xr));
        const int xcd = xr & 7;
        xchg[0] = xcd;
        xchg[1] = atomicAdd(&counters[xcd * 32], 1) & 31;
    }
    __syncthreads();
    const int xcd  = xchg[0];
    const int rank = xchg[1];
    __syncthreads();                  // reads done before hlo_ls reuse
    const int fbase = xcd * BPX;

    // ---- preload + split w_hh slice into bf16 hi/lo, XOR-swizzled ----
    {
        #pragma unroll
        for (int it = 0; it < 16; ++it) {
            const int idx = it * 256 + tid;        // [0,4096): lr(64) x kg(64)
            const int lr = idx >> 6, kg = idx & 63;
            const int grow = (lr >> 4) * Hh + rank * UPB + (lr & 15);
            const float4* src = (const float4*)(w_hh + (size_t)grow * Hh + kg * 8);
            const float4 f0 = src[0], f1 = src[1];
            const float f[8] = { f0.x, f0.y, f0.z, f0.w, f1.x, f1.y, f1.z, f1.w };
            bf16x8 vhi, vlo;
            #pragma unroll
            for (int j = 0; j < 8; ++j) {
                const unsigned short h = f2bf(f[j]);
                vhi[j] = (short)h;
                vlo[j] = (short)f2bf(f[j] - bf2f(h));
            }
            const int off = (lr * 1024 + kg * 16) ^ ((lr & 7) << 4);
            *(bf16x8*)((char*)wls_hi + off) = vhi;
            *(bf16x8*)((char*)wls_lo + off) = vlo;
        }
    }

    // ---- elementwise role: thread -> (u, b) ----
    const int u  = tid & 15;
    const int b_ = tid >> 4;                 // 0..15
    const int gj = rank * UPB + u;           // global hidden unit
    const int gb = xcd * NB + b_;            // global batch row
    float wih_r[4], bias_r[4];
    #pragma unroll
    for (int g = 0; g < 4; ++g) {
        wih_r[g]  = w_ih[g * Hh + gj];
        bias_r[g] = b_ih[g * Hh + gj] + b_hh[g * Hh + gj];
    }
    float creg = 0.0f;

    // ---- owner role: ranks 0..15 own batch row xcd*16+rank ----
    const bool owner = (rank < NB);
    const int  gb_own = xcd * NB + rank;
    float S1w[Cc], S2w[Cc], bfc_r[Cc];
    #pragma unroll
    for (int c = 0; c < Cc; ++c) { S1w[c] = 0.f; S2w[c] = 0.f; bfc_r[c] = b_fc[c]; }

    // MFMA fragment addressing (A = W rows of gate wv, B = h batches)
    const int arow  = wv * 16 + (lane & 15);
    const int aoff0 = arow * 1024 + ((lane >> 4) << 4);
    const int boff0 = (lane & 15) * 1024 + ((lane >> 4) << 4);
    const int xmask = (lane & 7) << 4;

    for (int t = 0; t <= Tt; ++t) {
        const int rb = t & 1, wb = rb ^ 1;

        // ---- A1: stage h_t hi/lo (16 x 512 bf16 each) into swizzled LDS ----
        if (t == 0) {
            const bf16x8 z = { 0, 0, 0, 0, 0, 0, 0, 0 };
            #pragma unroll
            for (int it = 0; it < 4; ++it) {
                const int idx = it * 256 + tid;
                const int row = idx >> 6, kg = idx & 63;
                const int off = (row * 1024 + kg * 16) ^ ((row & 7) << 4);
                *(bf16x8*)((char*)hhi_ls + off) = z;
                *(bf16x8*)((char*)hlo_ls + off) = z;
            }
        } else if (t < Tt) {
            const bf16x8* shi = (const bf16x8*)(hg_hi + (size_t)(rb * NXCD + xcd) * NB * Hh);
            const bf16x8* slo = (const bf16x8*)(hg_lo + (size_t)(rb * NXCD + xcd) * NB * Hh);
            #pragma unroll
            for (int it = 0; it < 4; ++it) {
                const int idx = it * 256 + tid;        // row*64 + kg
                const int row = idx >> 6, kg = idx & 63;
                const bf16x8 vhi = shi[idx];
                const bf16x8 vlo = slo[idx];
                const int off = (row * 1024 + kg * 16) ^ ((row & 7) << 4);
                *(bf16x8*)((char*)hhi_ls + off) = vhi;
                *(bf16x8*)((char*)hlo_ls + off) = vlo;
            }
        }

        // ---- A2: owner emits step t-1's outputs (reads same buffer as A1) ----
        if (t > 0 && wv == 0 && owner) {
            const size_t rbase = ((size_t)(rb * NXCD + xcd) * NB + rank) * Hh + lane * 8;
            const bf16x8 vh = *(const bf16x8*)(hg_hi + rbase);
            const bf16x8 vl = *(const bf16x8*)(hg_lo + rbase);
            float f[8];
            #pragma unroll
            for (int j = 0; j < 8; ++j)
                f[j] = bf2f((unsigned short)vh[j]) + bf2f((unsigned short)vl[j]);
            const float4 hA = make_float4(f[0], f[1], f[2], f[3]);
            const float4 hB = make_float4(f[4], f[5], f[6], f[7]);
            const float4* wt4 = (const float4*)w_t;
            const float4* wf4 = (const float4*)w_fc;
            float r[12];
            r[0] = dot4(hA, wt4[lane * 2])       + dot4(hB, wt4[lane * 2 + 1]);
            r[1] = dot4(hA, wt4[128 + lane * 2]) + dot4(hB, wt4[128 + lane * 2 + 1]);
            #pragma unroll
            for (int c = 0; c < Cc; ++c)
                r[2 + c] = dot4(hA, wf4[c * 128 + lane * 2])
                         + dot4(hB, wf4[c * 128 + lane * 2 + 1]);
            #pragma unroll
            for (int m = 1; m <= 32; m <<= 1)
                #pragma unroll
                for (int k2 = 0; k2 < 12; ++k2)
                    r[k2] += __shfl_xor(r[k2], m, 64);

            if (lane == 0) {
                const float a = r[0], b2 = r[1];
                float* po = out + ((size_t)gb_own * Tt + (t - 1)) * Cc;
                #pragma unroll
                for (int c = 0; c < Cc; ++c) {
                    const float hw = r[2 + c];
                    po[c] = hw + a * S1w[c] + S2w[c] + bfc_r[c];
                    S1w[c] += hw;
                    S2w[c] += b2 * hw;
                }
            }
        }
        if (t == Tt) break;

        const float xv = x[(size_t)gb * Tt + t];   // independent; issues early
        __syncthreads();

        // ---- B: gates GEMM 64x16x512 via 3-pass split-bf16 MFMA ----
        f32x4 acc0 = { 0.f, 0.f, 0.f, 0.f };
        f32x4 acc1 = { 0.f, 0.f, 0.f, 0.f };
        f32x4 acc2 = { 0.f, 0.f, 0.f, 0.f };
        #pragma unroll
        for (int kk = 0; kk < 16; ++kk) {
            const int ao = (aoff0 + kk * 64) ^ xmask;
            const int bo = (boff0 + kk * 64) ^ xmask;
            const bf16x8 ahi = *(const bf16x8*)((const char*)wls_hi + ao);
            const bf16x8 alo = *(const bf16x8*)((const char*)wls_lo + ao);
            const bf16x8 bhi = *(const bf16x8*)((const char*)hhi_ls + bo);
            const bf16x8 blo = *(const bf16x8*)((const char*)hlo_ls + bo);
            acc0 = __builtin_amdgcn_mfma_f32_16x16x32_bf16(ahi, bhi, acc0, 0, 0, 0);
            acc1 = __builtin_amdgcn_mfma_f32_16x16x32_bf16(ahi, blo, acc1, 0, 0, 0);
            acc2 = __builtin_amdgcn_mfma_f32_16x16x32_bf16(alo, bhi, acc2, 0, 0, 0);
        }
        __syncthreads();          // all LDS frag reads done before gbuf aliases

        // C/D layout: col=lane&15 (batch), row=(lane>>4)*4+reg (unit in tile)
        {
            const int unit0 = (lane >> 4) * 4;
            const int batch = lane & 15;
            #pragma unroll
            for (int r = 0; r < 4; ++r)
                gbuf[(wv * 16 + unit0 + r) * 20 + batch] = acc0[r] + acc1[r] + acc2[r];
        }
        __syncthreads();

        // ---- C: LSTM elementwise, write h hi/lo (plain stores -> XCD L2) ----
        {
            const float gi = gbuf[(0 * UPB + u) * 20 + b_] + xv * wih_r[0] + bias_r[0];
            const float gf = gbuf[(1 * UPB + u) * 20 + b_] + xv * wih_r[1] + bias_r[1];
            const float gg = gbuf[(2 * UPB + u) * 20 + b_] + xv * wih_r[2] + bias_r[2];
            const float go = gbuf[(3 * UPB + u) * 20 + b_] + xv * wih_r[3] + bias_r[3];
            creg = fsig(gf) * creg + fsig(gi) * ftanh(gg);
            const float hnew = fsig(go) * ftanh(creg);
            const unsigned short hb = f2bf(hnew);
            const unsigned short lb = f2bf(hnew - bf2f(hb));
            const size_t hoff = ((size_t)(wb * NXCD + xcd) * NB + b_) * Hh + gj;
            hg_hi[hoff] = hb;
            hg_lo[hoff] = lb;
        }
        __syncthreads();   // vmcnt(0) drained before barrier: h visible in L2

        // ---- D: plain-store flag (ordered after h by the drain above) ----
        if (tid == 0)
            *(volatile int*)(flags + fbase + rank) = t + 1;

        // ---- E: lanes 0-31 of wave 0 poll 32 flags via L2 (no atomics) ----
        if (tid < 32) {
            const volatile int* fl = (const volatile int*)(flags + fbase + tid);
            int v = *fl;
            while (__any(v < t + 1)) {
                __builtin_amdgcn_s_sleep(1);
                asm volatile("buffer_inv\n\ts_waitcnt vmcnt(0)" ::: "memory");
                v = *fl;
            }
            // final L1 invalidate: peers' h (already in shared XCD L2) now visible
            asm volatile("buffer_inv\n\ts_waitcnt vmcnt(0)" ::: "memory");
        }
        __syncthreads();   // block released with clean L1
    }
}

extern "C" void kernel_launch(void* const* d_in, const int* in_sizes, int n_in,
                              void* d_out, int out_size, void* d_ws, size_t ws_size,
                              hipStream_t stream)
{
    const float* xp  = (const float*)d_in[0];
    const float* wih = (const float*)d_in[1];
    const float* whh = (const float*)d_in[2];
    const float* bih = (const float*)d_in[3];
    const float* bhh = (const float*)d_in[4];
    const float* wt  = (const float*)d_in[5];
    const float* wfc = (const float*)d_in[6];
    const float* bfc = (const float*)d_in[7];
    float* outp = (float*)d_out;
    float* ws   = (float*)d_ws;

    // zero flags + rank counters each call (graph-capturable)
    (void)hipMemsetAsync(d_ws, 0, 4096, stream);

    hipLaunchKernelGGL(lstm_fused, dim3(GRID), dim3(THREADS), 0, stream,
                       xp, wih, whh, bih, bhh, wt, wfc, bfc, outp, ws);
}